// Round 1
// baseline (3418.095 us; speedup 1.0000x reference)
//
#include <hip/hip_runtime.h>
#include <hip/hip_bf16.h>
#include <float.h>

#define N_PTS 65536
#define D_DIM 512
#define K_EMB 4096
#define BM 128
#define BN 128
#define BK 16
#define LDP 132   // padded leading dim: 132%4==0 (16B-aligned float4), 132%32==4 -> 2-way banks (free)

// ---------------- Kernel 1: row norms for E and X ----------------
__global__ void vq_norms(const float* __restrict__ X, const float* __restrict__ E,
                         float* __restrict__ xn, float* __restrict__ en) {
  const int wave = threadIdx.x >> 6;
  const int lane = threadIdx.x & 63;
  const int row = blockIdx.x * 4 + wave;
  const float* src;
  float* dst;
  if (row < K_EMB) {
    src = E + (size_t)row * D_DIM;
    dst = en + row;
  } else {
    const int r = row - K_EMB;
    src = X + (size_t)r * D_DIM;
    dst = xn + r;
  }
  float s = 0.f;
#pragma unroll
  for (int h = 0; h < 2; ++h) {
    float4 v = *(const float4*)(src + h * 256 + lane * 4);
    s += v.x * v.x + v.y * v.y + v.z * v.z + v.w * v.w;
  }
#pragma unroll
  for (int m = 32; m >= 1; m >>= 1) s += __shfl_xor(s, m);
  if (lane == 0) *dst = s;
}

// ---------------- Kernel 2: fused distance-GEMM + argmin + gather + loss ----------------
__global__ __launch_bounds__(256) void vq_main(
    const float* __restrict__ X, const float* __restrict__ E,
    const float* __restrict__ xn, const float* __restrict__ en,
    float* __restrict__ out, double* __restrict__ loss_sum) {
  __shared__ float Xs[BK][LDP];
  __shared__ float Es[BK][LDP];
  __shared__ int row_idx[BM];
  __shared__ float wsum[4];

  const int tid = threadIdx.x;
  const int tc = tid & 15;
  const int tr = tid >> 4;
  const int row0 = blockIdx.x * BM;

  // this thread's 8 rows: tr*4+i (i<4) and 64+tr*4+(i-4)
  float xnr[8];
#pragma unroll
  for (int i = 0; i < 8; ++i) {
    const int r = (i < 4) ? (tr * 4 + i) : (64 + tr * 4 + i - 4);
    xnr[i] = xn[row0 + r];
  }

  float minv[8];
  int mini[8];
#pragma unroll
  for (int i = 0; i < 8; ++i) { minv[i] = FLT_MAX; mini[i] = 0; }

  for (int kc = 0; kc < K_EMB; kc += BN) {
    float enr[8];
#pragma unroll
    for (int j = 0; j < 8; ++j) {
      const int c = (j < 4) ? (tc * 4 + j) : (64 + tc * 4 + j - 4);
      enr[j] = en[kc + c];
    }
    float acc[8][8];
#pragma unroll
    for (int i = 0; i < 8; ++i)
#pragma unroll
      for (int j = 0; j < 8; ++j) acc[i][j] = 0.f;

    for (int d0 = 0; d0 < D_DIM; d0 += BK) {
      __syncthreads();  // protect LDS from previous stage's readers
#pragma unroll
      for (int h = 0; h < 2; ++h) {
        const int f = tid + h * 256;
        const int r = f >> 2;            // 0..127
        const int kq = (f & 3) * 4;      // 0,4,8,12
        float4 vx = *(const float4*)(X + (size_t)(row0 + r) * D_DIM + d0 + kq);
        float4 ve = *(const float4*)(E + (size_t)(kc + r) * D_DIM + d0 + kq);
        Xs[kq + 0][r] = vx.x; Xs[kq + 1][r] = vx.y; Xs[kq + 2][r] = vx.z; Xs[kq + 3][r] = vx.w;
        Es[kq + 0][r] = ve.x; Es[kq + 1][r] = ve.y; Es[kq + 2][r] = ve.z; Es[kq + 3][r] = ve.w;
      }
      __syncthreads();
#pragma unroll
      for (int k = 0; k < BK; ++k) {
        float a[8], b[8];
        *(float4*)(a)     = *(const float4*)(&Xs[k][tr * 4]);
        *(float4*)(a + 4) = *(const float4*)(&Xs[k][64 + tr * 4]);
        *(float4*)(b)     = *(const float4*)(&Es[k][tc * 4]);
        *(float4*)(b + 4) = *(const float4*)(&Es[k][64 + tc * 4]);
#pragma unroll
        for (int i = 0; i < 8; ++i)
#pragma unroll
          for (int j = 0; j < 8; ++j)
            acc[i][j] = fmaf(a[i], b[j], acc[i][j]);
      }
    }
    // fold this K-chunk into the running argmin (ascending c + strict < == np tie-break)
#pragma unroll
    for (int i = 0; i < 8; ++i) {
#pragma unroll
      for (int j = 0; j < 8; ++j) {
        const int c = kc + ((j < 4) ? (tc * 4 + j) : (64 + tc * 4 + j - 4));
        const float d = fmaf(-2.f, acc[i][j], xnr[i] + enr[j]);
        if (d < minv[i]) { minv[i] = d; mini[i] = c; }
      }
    }
  }

  // cross-lane argmin reduce: the 16 threads sharing a row are lanes differing in low 4 bits
#pragma unroll
  for (int i = 0; i < 8; ++i) {
    float v = minv[i];
    int ix = mini[i];
#pragma unroll
    for (int m = 1; m <= 8; m <<= 1) {
      const float v2 = __shfl_xor(v, m);
      const int ix2 = __shfl_xor(ix, m);
      if (v2 < v || (v2 == v && ix2 < ix)) { v = v2; ix = ix2; }
    }
    if (tc == 0) {
      const int r = (i < 4) ? (tr * 4 + i) : (64 + tr * 4 + i - 4);
      row_idx[r] = ix;
    }
  }
  __syncthreads();

  // gather + loss: 2 threads per row, fully coalesced float4
  float lsum = 0.f;
  const int half = tid >> 7;
  const int c4 = (tid & 127) * 4;
  for (int r0 = 0; r0 < BM; r0 += 2) {
    const int r = r0 + half;
    const int idx = row_idx[r];
    const float4 ev = *(const float4*)(E + (size_t)idx * D_DIM + c4);
    const float4 xv = *(const float4*)(X + (size_t)(row0 + r) * D_DIM + c4);
    *(float4*)(out + (size_t)(row0 + r) * D_DIM + c4) = ev;
    const float dx = ev.x - xv.x, dy = ev.y - xv.y, dz = ev.z - xv.z, dw = ev.w - xv.w;
    lsum += dx * dx + dy * dy + dz * dz + dw * dw;
  }
#pragma unroll
  for (int m = 32; m >= 1; m >>= 1) lsum += __shfl_xor(lsum, m);
  const int lane = tid & 63;
  const int wave = tid >> 6;
  if (lane == 0) wsum[wave] = lsum;
  __syncthreads();
  if (tid == 0) {
    const double t = (double)wsum[0] + (double)wsum[1] + (double)wsum[2] + (double)wsum[3];
    atomicAdd(loss_sum, t);
  }
}

// ---------------- Kernel 3: finalize loss scalar ----------------
__global__ void vq_finalize(const double* __restrict__ loss_sum, float* __restrict__ out) {
  if (threadIdx.x == 0 && blockIdx.x == 0) {
    out[(size_t)N_PTS * D_DIM] =
        (float)(1.25 * (*loss_sum) / ((double)N_PTS * (double)D_DIM));
  }
}

extern "C" void kernel_launch(void* const* d_in, const int* in_sizes, int n_in,
                              void* d_out, int out_size, void* d_ws, size_t ws_size,
                              hipStream_t stream) {
  const float* X = (const float*)d_in[0];
  const float* E = (const float*)d_in[1];
  float* out = (float*)d_out;

  // ws layout: en[K] | xn[N] | double loss_sum  (278536 bytes total)
  float* en = (float*)d_ws;
  float* xn = en + K_EMB;
  double* loss_sum = (double*)((char*)d_ws + (size_t)(K_EMB + N_PTS) * sizeof(float));

  hipMemsetAsync(loss_sum, 0, sizeof(double), stream);
  hipLaunchKernelGGL(vq_norms, dim3((K_EMB + N_PTS) / 4), dim3(256), 0, stream,
                     X, E, xn, en);
  hipLaunchKernelGGL(vq_main, dim3(N_PTS / BM), dim3(256), 0, stream,
                     X, E, xn, en, out, loss_sum);
  hipLaunchKernelGGL(vq_finalize, dim3(1), dim3(64), 0, stream, loss_sum, out);
}

// Round 2
// 938.574 us; speedup vs baseline: 3.6418x; 3.6418x over previous
//
#include <hip/hip_runtime.h>
#include <hip/hip_fp16.h>
#include <float.h>

typedef _Float16 f16x8 __attribute__((ext_vector_type(8)));
typedef float f32x4 __attribute__((ext_vector_type(4)));

#define N_PTS 65536
#define D_DIM 512
#define K_EMB 4096
#define BM 128
#define BN 128
#define NCHUNK 32   // K_EMB / BN
#define BK 32       // K halves per step (one MFMA K)
#define NSTEP 16    // D_DIM / BK
#define NS (NCHUNK * NSTEP)

// ---------------- Kernel 1: E row norms ----------------
__global__ void vq_en(const float* __restrict__ E, float* __restrict__ en) {
  const int wave = threadIdx.x >> 6;
  const int lane = threadIdx.x & 63;
  const int row = blockIdx.x * 4 + wave;
  const float* src = E + (size_t)row * D_DIM;
  float s = 0.f;
#pragma unroll
  for (int h = 0; h < 2; ++h) {
    float4 v = *(const float4*)(src + h * 256 + lane * 4);
    s += v.x * v.x + v.y * v.y + v.z * v.z + v.w * v.w;
  }
#pragma unroll
  for (int m = 32; m >= 1; m >>= 1) s += __shfl_xor(s, m);
  if (lane == 0) en[row] = s;
}

__device__ __forceinline__ void cvt_hl(const float4 v, f16x8& H, f16x8& L, const int b) {
  _Float16 h;
  h = (_Float16)v.x; H[b + 0] = h; L[b + 0] = (_Float16)(v.x - (float)h);
  h = (_Float16)v.y; H[b + 1] = h; L[b + 1] = (_Float16)(v.y - (float)h);
  h = (_Float16)v.z; H[b + 2] = h; L[b + 2] = (_Float16)(v.z - (float)h);
  h = (_Float16)v.w; H[b + 3] = h; L[b + 3] = (_Float16)(v.w - (float)h);
}

// ---------------- Kernel 2: fused split-fp16 MFMA distance GEMM + argmin + gather + loss ----
__global__ __launch_bounds__(256, 2) void vq_main(
    const float* __restrict__ X, const float* __restrict__ E,
    const float* __restrict__ en, float* __restrict__ outp,
    double* __restrict__ loss_sum) {
  __shared__ __align__(16) _Float16 Xh[BM][BK];
  __shared__ __align__(16) _Float16 Xl[BM][BK];
  __shared__ __align__(16) _Float16 Eh[BN][BK];
  __shared__ __align__(16) _Float16 El[BN][BK];
  __shared__ float rval[2][64][2];
  __shared__ int   rixd[2][64][2];
  __shared__ int   fin_idx[BM];
  __shared__ float wsum[4];

  const int tid  = threadIdx.x;
  const int lane = tid & 63;
  const int wid  = tid >> 6;
  const int wm   = wid >> 1;      // wave row-half (0..1)
  const int wn   = wid & 1;       // wave col-half (0..1)
  const int l15  = lane & 15;
  const int lq   = lane >> 4;     // 0..3
  const int row0 = blockIdx.x * BM;

  // staging assignment: 2 threads per row, 16 floats each
  const int srow  = tid >> 1;
  const int seg16 = (tid & 1) * 16;
  const float* Xbase = X + (size_t)(row0 + srow) * D_DIM + seg16;

  float4 xgA[4], egA[4], xgB[4], egB[4];
#pragma unroll
  for (int e = 0; e < 4; ++e) xgA[e] = *(const float4*)(Xbase + e * 4);
  {
    const float* ep = E + (size_t)srow * D_DIM + seg16;
#pragma unroll
    for (int e = 0; e < 4; ++e) egA[e] = *(const float4*)(ep + e * 4);
  }

  float minv[16];
  int   mini[16];
#pragma unroll
  for (int k = 0; k < 16; ++k) { minv[k] = FLT_MAX; mini[k] = 0; }

  f32x4 acc[4][4];
  float enj[4];

#define STEP(S, XG, EG, XGN, EGN)                                              \
  {                                                                            \
    const int t = (S) & (NSTEP - 1);                                           \
    const int chunk = (S) >> 4;                                                \
    if (t == 0) {                                                              \
      _Pragma("unroll") for (int j = 0; j < 4; ++j)                            \
          enj[j] = en[chunk * BN + wn * 64 + j * 16 + l15];                    \
      _Pragma("unroll") for (int i = 0; i < 4; ++i)                            \
          _Pragma("unroll") for (int j = 0; j < 4; ++j)                        \
              acc[i][j] = (f32x4)(0.f);                                        \
    }                                                                          \
    __syncthreads();                                                           \
    {                                                                          \
      f16x8 H0, H1, L0, L1;                                                    \
      cvt_hl(XG[0], H0, L0, 0); cvt_hl(XG[1], H0, L0, 4);                      \
      cvt_hl(XG[2], H1, L1, 0); cvt_hl(XG[3], H1, L1, 4);                      \
      *(f16x8*)&Xh[srow][seg16]     = H0;                                      \
      *(f16x8*)&Xh[srow][seg16 + 8] = H1;                                      \
      *(f16x8*)&Xl[srow][seg16]     = L0;                                      \
      *(f16x8*)&Xl[srow][seg16 + 8] = L1;                                      \
      cvt_hl(EG[0], H0, L0, 0); cvt_hl(EG[1], H0, L0, 4);                      \
      cvt_hl(EG[2], H1, L1, 0); cvt_hl(EG[3], H1, L1, 4);                      \
      *(f16x8*)&Eh[srow][seg16]     = H0;                                      \
      *(f16x8*)&Eh[srow][seg16 + 8] = H1;                                      \
      *(f16x8*)&El[srow][seg16]     = L0;                                      \
      *(f16x8*)&El[srow][seg16 + 8] = L1;                                      \
    }                                                                          \
    if ((S) + 1 < NS) {                                                        \
      const int t1 = ((S) + 1) & (NSTEP - 1);                                  \
      const int c1 = ((S) + 1) >> 4;                                           \
      const float* xp = Xbase + t1 * BK;                                       \
      const float* ep2 = E + (size_t)(c1 * BN + srow) * D_DIM + t1 * BK + seg16; \
      _Pragma("unroll") for (int e = 0; e < 4; ++e)                            \
          XGN[e] = *(const float4*)(xp + e * 4);                               \
      _Pragma("unroll") for (int e = 0; e < 4; ++e)                            \
          EGN[e] = *(const float4*)(ep2 + e * 4);                              \
    }                                                                          \
    __syncthreads();                                                           \
    {                                                                          \
      const int qo = lq * 8;                                                   \
      f16x8 bh[4], bl[4];                                                      \
      _Pragma("unroll") for (int j = 0; j < 4; ++j) {                          \
        bh[j] = *(const f16x8*)&Eh[wn * 64 + j * 16 + l15][qo];                \
        bl[j] = *(const f16x8*)&El[wn * 64 + j * 16 + l15][qo];                \
      }                                                                        \
      _Pragma("unroll") for (int i = 0; i < 4; ++i) {                          \
        const f16x8 ah = *(const f16x8*)&Xh[wm * 64 + i * 16 + l15][qo];       \
        const f16x8 al = *(const f16x8*)&Xl[wm * 64 + i * 16 + l15][qo];       \
        _Pragma("unroll") for (int j = 0; j < 4; ++j) {                        \
          acc[i][j] = __builtin_amdgcn_mfma_f32_16x16x32_f16(ah, bh[j], acc[i][j], 0, 0, 0); \
          acc[i][j] = __builtin_amdgcn_mfma_f32_16x16x32_f16(ah, bl[j], acc[i][j], 0, 0, 0); \
          acc[i][j] = __builtin_amdgcn_mfma_f32_16x16x32_f16(al, bh[j], acc[i][j], 0, 0, 0); \
        }                                                                      \
      }                                                                        \
    }                                                                          \
    if (t == NSTEP - 1) {                                                      \
      _Pragma("unroll") for (int i = 0; i < 4; ++i)                            \
          _Pragma("unroll") for (int j = 0; j < 4; ++j) {                      \
        const int c = chunk * BN + wn * 64 + j * 16 + l15;                     \
        _Pragma("unroll") for (int r = 0; r < 4; ++r) {                        \
          const float dd = fmaf(-2.f, acc[i][j][r], enj[j]);                   \
          const int k = i * 4 + r;                                             \
          if (dd < minv[k]) { minv[k] = dd; mini[k] = c; }                     \
        }                                                                      \
      }                                                                        \
    }                                                                          \
  }

  for (int s = 0; s < NS; s += 2) {
    STEP(s, xgA, egA, xgB, egB);
    STEP(s + 1, xgB, egB, xgA, egA);
  }
#undef STEP

  // cross-lane argmin reduce within each 16-lane col group
#pragma unroll
  for (int k = 0; k < 16; ++k) {
    float v = minv[k];
    int ix = mini[k];
#pragma unroll
    for (int m = 1; m <= 8; m <<= 1) {
      const float v2 = __shfl_xor(v, m);
      const int ix2 = __shfl_xor(ix, m);
      if (v2 < v || (v2 == v && ix2 < ix)) { v = v2; ix = ix2; }
    }
    if (l15 == 0) {
      const int lrow = (k >> 2) * 16 + lq * 4 + (k & 3);
      rval[wm][lrow][wn] = v;
      rixd[wm][lrow][wn] = ix;
    }
  }
  __syncthreads();
  if (tid < BM) {
    const int wm_ = tid >> 6, lrow = tid & 63;
    const float v0 = rval[wm_][lrow][0], v1 = rval[wm_][lrow][1];
    const int i0 = rixd[wm_][lrow][0], i1 = rixd[wm_][lrow][1];
    fin_idx[tid] = (v1 < v0 || (v1 == v0 && i1 < i0)) ? i1 : i0;
  }
  __syncthreads();

  // gather + loss: 2 threads per row, coalesced float4
  float lsum = 0.f;
  const int half = tid >> 7;
  const int c4 = (tid & 127) * 4;
  for (int r0 = 0; r0 < BM; r0 += 2) {
    const int r = r0 + half;
    const int idx = fin_idx[r];
    const float4 ev = *(const float4*)(E + (size_t)idx * D_DIM + c4);
    const float4 xv = *(const float4*)(X + (size_t)(row0 + r) * D_DIM + c4);
    *(float4*)(outp + (size_t)(row0 + r) * D_DIM + c4) = ev;
    const float dx = ev.x - xv.x, dy = ev.y - xv.y, dz = ev.z - xv.z, dw = ev.w - xv.w;
    lsum += dx * dx + dy * dy + dz * dz + dw * dw;
  }
#pragma unroll
  for (int m = 32; m >= 1; m >>= 1) lsum += __shfl_xor(lsum, m);
  if (lane == 0) wsum[wid] = lsum;
  __syncthreads();
  if (tid == 0) {
    const double t = (double)wsum[0] + (double)wsum[1] + (double)wsum[2] + (double)wsum[3];
    atomicAdd(loss_sum, t);
  }
}

// ---------------- Kernel 3: finalize loss ----------------
__global__ void vq_finalize(const double* __restrict__ loss_sum, float* __restrict__ outp) {
  if (threadIdx.x == 0 && blockIdx.x == 0) {
    outp[(size_t)N_PTS * D_DIM] =
        (float)(1.25 * (*loss_sum) / ((double)N_PTS * (double)D_DIM));
  }
}

extern "C" void kernel_launch(void* const* d_in, const int* in_sizes, int n_in,
                              void* d_out, int out_size, void* d_ws, size_t ws_size,
                              hipStream_t stream) {
  const float* X = (const float*)d_in[0];
  const float* E = (const float*)d_in[1];
  float* outp = (float*)d_out;

  // ws layout: en[K_EMB] floats | double loss_sum
  float* en = (float*)d_ws;
  double* loss_sum = (double*)((char*)d_ws + K_EMB * sizeof(float));

  hipMemsetAsync(loss_sum, 0, sizeof(double), stream);
  hipLaunchKernelGGL(vq_en, dim3(K_EMB / 4), dim3(256), 0, stream, E, en);
  hipLaunchKernelGGL(vq_main, dim3(N_PTS / BM), dim3(256), 0, stream,
                     X, E, en, outp, loss_sum);
  hipLaunchKernelGGL(vq_finalize, dim3(1), dim3(64), 0, stream, loss_sum, outp);
}

// Round 3
// 840.928 us; speedup vs baseline: 4.0647x; 1.1161x over previous
//
#include <hip/hip_runtime.h>
#include <hip/hip_fp16.h>
#include <float.h>

typedef _Float16 f16x8 __attribute__((ext_vector_type(8)));
typedef float f32x4 __attribute__((ext_vector_type(4)));

#define N_PTS 65536
#define D_DIM 512
#define K_EMB 4096

// ---------- fast-path geometry ----------
#define FBM 256            // rows per block
#define FBN 256            // cols per chunk
#define NCH 16             // K_EMB / FBN
#define NDS 16             // D_DIM / 32
#define NT  256            // NCH * NDS total steps
#define TILE_B 32768       // bytes per (step) tile pair: H 16KB + L 16KB

#define GLOAD16(gsrc, ldst)                                                    \
  __builtin_amdgcn_global_load_lds(                                            \
      (const __attribute__((address_space(1))) void*)(gsrc),                   \
      (__attribute__((address_space(3))) void*)(ldst), 16, 0, 0)

#define BAR() asm volatile("s_barrier" ::: "memory")
#define VMCNT(n) asm volatile("s_waitcnt vmcnt(" #n ")" ::: "memory")

// ---------------- Kernel: E row norms ----------------
__global__ void vq_en(const float* __restrict__ E, float* __restrict__ en) {
  const int wave = threadIdx.x >> 6;
  const int lane = threadIdx.x & 63;
  const int row = blockIdx.x * 4 + wave;
  const float* src = E + (size_t)row * D_DIM;
  float s = 0.f;
#pragma unroll
  for (int h = 0; h < 2; ++h) {
    float4 v = *(const float4*)(src + h * 256 + lane * 4);
    s += v.x * v.x + v.y * v.y + v.z * v.z + v.w * v.w;
  }
#pragma unroll
  for (int m = 32; m >= 1; m >>= 1) s += __shfl_xor(s, m);
  if (lane == 0) en[row] = s;
}

__device__ __forceinline__ void cvt_hl(const float4 v, f16x8& H, f16x8& L, const int b) {
  _Float16 h;
  h = (_Float16)v.x; H[b + 0] = h; L[b + 0] = (_Float16)(v.x - (float)h);
  h = (_Float16)v.y; H[b + 1] = h; L[b + 1] = (_Float16)(v.y - (float)h);
  h = (_Float16)v.z; H[b + 2] = h; L[b + 2] = (_Float16)(v.z - (float)h);
  h = (_Float16)v.w; H[b + 3] = h; L[b + 3] = (_Float16)(v.w - (float)h);
}

// ---------------- Kernel: precompute hi/lo tiles in MFMA-fragment order -----
// Tile (mt/ct, ds) = 32KB: [H 16KB][L 16KB]; within each: element
// (row=rg*16+l15, k=kq*8+h) at byte ((rg*4+kq)*16 + l15)*16 + h*2.
__global__ void vq_precvt(const float* __restrict__ X, const float* __restrict__ E,
                          char* __restrict__ Xpre, char* __restrict__ Epre) {
  const int bid = blockIdx.x;
  const float* src;
  char* dst;
  if (bid < 4096) {            // X: 256 mt * 16 ds
    const int mt = bid >> 4, ds = bid & 15;
    src = X + (size_t)mt * 256 * D_DIM + ds * 32;
    dst = Xpre + (size_t)bid * TILE_B;
  } else {                     // E: 16 ct * 16 ds
    const int b = bid - 4096;
    const int ct = b >> 4, ds = b & 15;
    src = E + (size_t)ct * 256 * D_DIM + ds * 32;
    dst = Epre + (size_t)b * TILE_B;
  }
  const int r = threadIdx.x;   // 256 threads = 256 rows
  const float* row = src + (size_t)r * D_DIM;
  float4 v[8];
#pragma unroll
  for (int q = 0; q < 8; ++q) v[q] = *(const float4*)(row + q * 4);
  f16x8 H[4], L[4];
#pragma unroll
  for (int kq = 0; kq < 4; ++kq) {
    cvt_hl(v[kq * 2], H[kq], L[kq], 0);
    cvt_hl(v[kq * 2 + 1], H[kq], L[kq], 4);
  }
  const int rg = r >> 4, l15 = r & 15;
#pragma unroll
  for (int kq = 0; kq < 4; ++kq) {
    *(f16x8*)(dst + ((size_t)((rg * 4 + kq) * 16 + l15)) * 16) = H[kq];
    *(f16x8*)(dst + 16384 + ((size_t)((rg * 4 + kq) * 16 + l15)) * 16) = L[kq];
  }
}

// ---------------- Fast main kernel: 3-phase counted-vmcnt MFMA loop ---------
__global__ __launch_bounds__(512, 1) void vq_main_fast(
    const char* __restrict__ Xpre, const char* __restrict__ Epre,
    const float* __restrict__ en, const float* __restrict__ X,
    const float* __restrict__ E, float* __restrict__ outp,
    double* __restrict__ loss_sum) {
  __shared__ __align__(16) char buf[2][65536];  // per buf: XH|XL|EH|EL 16KB each
  __shared__ __align__(16) float en_lds[K_EMB];
  __shared__ float argv_[2][FBM];
  __shared__ int argi_[2][FBM];
  __shared__ int fin_idx[FBM];
  __shared__ float wsum[8];

  const int tid = threadIdx.x;
  const int lane = tid & 63;
  const int wid = tid >> 6;
  const int wm = wid >> 1;   // 0..3  (row quarter: 64 rows)
  const int wn = wid & 1;    // 0..1  (col half: 128 cols)
  const int l15 = lane & 15;
  const int lq = lane >> 4;
  const int mt = blockIdx.x;

  const char* Xbase = Xpre + (size_t)mt * (NDS * TILE_B);

#define STAGE_X(g1)                                                            \
  {                                                                            \
    const char* s_ = Xbase + (size_t)((g1) & 15) * TILE_B + wid * 4096 + lane * 16; \
    char* d_ = &buf[(g1) & 1][0] + wid * 4096;                                 \
    GLOAD16(s_, d_); GLOAD16(s_ + 1024, d_ + 1024);                            \
    GLOAD16(s_ + 2048, d_ + 2048); GLOAD16(s_ + 3072, d_ + 3072);              \
  }
#define STAGE_EH(g1)                                                           \
  {                                                                            \
    const char* s_ = Epre + (size_t)(g1) * TILE_B + wid * 2048 + lane * 16;    \
    char* d_ = &buf[(g1) & 1][32768] + wid * 2048;                             \
    GLOAD16(s_, d_); GLOAD16(s_ + 1024, d_ + 1024);                            \
  }
#define STAGE_EL(g1)                                                           \
  {                                                                            \
    const char* s_ = Epre + (size_t)(g1) * TILE_B + 16384 + wid * 2048 + lane * 16; \
    char* d_ = &buf[(g1) & 1][49152] + wid * 2048;                             \
    GLOAD16(s_, d_); GLOAD16(s_ + 1024, d_ + 1024);                            \
  }

  // ---- prologue: en table (oldest), then step-0 quarters in steady order ----
  {
    const char* s_ = (const char*)en + wid * 2048 + lane * 16;
    char* d_ = (char*)en_lds + wid * 2048;
    GLOAD16(s_, d_); GLOAD16(s_ + 1024, d_ + 1024);
  }
  STAGE_X(0);
  STAGE_EH(0);
  STAGE_EL(0);
  VMCNT(2);   // en, XH/XL(0), EH(0) complete; EL(0) may be outstanding
  BAR();

  f32x4 acc[4][8];
#pragma unroll
  for (int i = 0; i < 4; ++i)
#pragma unroll
    for (int j = 0; j < 8; ++j) acc[i][j] = (f32x4)(0.f);
  float minv[16];
  int mini[16];
#pragma unroll
  for (int k = 0; k < 16; ++k) { minv[k] = FLT_MAX; mini[k] = 0; }

  f16x8 AH[4], BH[8];

  for (int g = 0; g < NT; ++g) {
    const char* XB = &buf[g & 1][0];
    const char* EB = &buf[g & 1][32768];

    // ---------------- phase 1: hi*hi ----------------
#pragma unroll
    for (int i = 0; i < 4; ++i)
      AH[i] = *(const f16x8*)(XB + (wm * 4 + i) * 1024 + lane * 16);
#pragma unroll
    for (int j = 0; j < 8; ++j)
      BH[j] = *(const f16x8*)(EB + (wn * 8 + j) * 1024 + lane * 16);
    if (g + 1 < NT) { STAGE_X(g + 1); VMCNT(4); } else { VMCNT(0); }
    BAR();
    __builtin_amdgcn_s_setprio(1);
#pragma unroll
    for (int i = 0; i < 4; ++i)
#pragma unroll
      for (int j = 0; j < 8; ++j)
        acc[i][j] = __builtin_amdgcn_mfma_f32_16x16x32_f16(AH[i], BH[j], acc[i][j], 0, 0, 0);
    __builtin_amdgcn_s_setprio(0);
    BAR();

    // ---------------- phase 2: hi*lo (A hi, B lo) ----------------
    if (g + 1 < NT) STAGE_EH(g + 1);
    BAR();
    __builtin_amdgcn_s_setprio(1);
#pragma unroll
    for (int j = 0; j < 8; ++j) {
      const f16x8 blj = *(const f16x8*)(EB + 16384 + (wn * 8 + j) * 1024 + lane * 16);
#pragma unroll
      for (int i = 0; i < 4; ++i)
        acc[i][j] = __builtin_amdgcn_mfma_f32_16x16x32_f16(AH[i], blj, acc[i][j], 0, 0, 0);
    }
    __builtin_amdgcn_s_setprio(0);
    BAR();

    // ---------------- phase 3: lo*hi (A lo, B hi) ----------------
    if (g + 1 < NT) { STAGE_EL(g + 1); VMCNT(2); }
    BAR();
    __builtin_amdgcn_s_setprio(1);
#pragma unroll
    for (int i = 0; i < 4; ++i) {
      const f16x8 ali = *(const f16x8*)(XB + 16384 + (wm * 4 + i) * 1024 + lane * 16);
#pragma unroll
      for (int j = 0; j < 8; ++j)
        acc[i][j] = __builtin_amdgcn_mfma_f32_16x16x32_f16(ali, BH[j], acc[i][j], 0, 0, 0);
    }
    __builtin_amdgcn_s_setprio(0);
    BAR();

    // ---------------- chunk end: fold argmin, reset acc ----------------
    if ((g & 15) == 15) {
      const int c = g >> 4;
#pragma unroll
      for (int j = 0; j < 8; ++j) {
        const int col = c * 256 + wn * 128 + j * 16 + l15;
        const float ej = en_lds[col];
#pragma unroll
        for (int i = 0; i < 4; ++i)
#pragma unroll
          for (int r = 0; r < 4; ++r) {
            const float dd = fmaf(-2.f, acc[i][j][r], ej);
            const int k = i * 4 + r;
            if (dd < minv[k]) { minv[k] = dd; mini[k] = col; }
          }
      }
#pragma unroll
      for (int i = 0; i < 4; ++i)
#pragma unroll
        for (int j = 0; j < 8; ++j) acc[i][j] = (f32x4)(0.f);
    }
  }
#undef STAGE_X
#undef STAGE_EH
#undef STAGE_EL

  // ---- cross-lane argmin reduce (16 l15 lanes share a row-slot) ----
#pragma unroll
  for (int k = 0; k < 16; ++k) {
    float v = minv[k];
    int ix = mini[k];
#pragma unroll
    for (int m = 1; m <= 8; m <<= 1) {
      const float v2 = __shfl_xor(v, m);
      const int ix2 = __shfl_xor(ix, m);
      if (v2 < v || (v2 == v && ix2 < ix)) { v = v2; ix = ix2; }
    }
    if (l15 == 0) {
      const int row = wm * 64 + (k >> 2) * 16 + lq * 4 + (k & 3);
      argv_[wn][row] = v;
      argi_[wn][row] = ix;
    }
  }
  __syncthreads();
  if (tid < FBM) {
    const float v0 = argv_[0][tid], v1 = argv_[1][tid];
    const int i0 = argi_[0][tid], i1 = argi_[1][tid];
    fin_idx[tid] = (v1 < v0 || (v1 == v0 && i1 < i0)) ? i1 : i0;
  }
  __syncthreads();

  // ---- gather + loss: 4 rows in flight, coalesced float4 ----
  float lsum = 0.f;
  const int half = tid >> 7;        // 0..3
  const int c4 = (tid & 127) * 4;
  const int row0 = mt * FBM;
  for (int r0 = 0; r0 < FBM; r0 += 4) {
    const int r = r0 + half;
    const int idx = fin_idx[r];
    const float4 ev = *(const float4*)(E + (size_t)idx * D_DIM + c4);
    const float4 xv = *(const float4*)(X + (size_t)(row0 + r) * D_DIM + c4);
    *(float4*)(outp + (size_t)(row0 + r) * D_DIM + c4) = ev;
    const float dx = ev.x - xv.x, dy = ev.y - xv.y, dz = ev.z - xv.z, dw = ev.w - xv.w;
    lsum += dx * dx + dy * dy + dz * dz + dw * dw;
  }
#pragma unroll
  for (int m = 32; m >= 1; m >>= 1) lsum += __shfl_xor(lsum, m);
  if (lane == 0) wsum[wid] = lsum;
  __syncthreads();
  if (tid == 0) {
    double t = 0.0;
#pragma unroll
    for (int w = 0; w < 8; ++w) t += (double)wsum[w];
    atomicAdd(loss_sum, t);
  }
}

// ================= round-2 fallback kernel (ws too small) =================
#define BM 128
#define BN 128
#define NCHUNK 32
#define BK 32
#define NSTEP 16
#define NS (NCHUNK * NSTEP)

__global__ __launch_bounds__(256, 2) void vq_main_r2(
    const float* __restrict__ X, const float* __restrict__ E,
    const float* __restrict__ en, float* __restrict__ outp,
    double* __restrict__ loss_sum) {
  __shared__ __align__(16) _Float16 Xh[BM][BK];
  __shared__ __align__(16) _Float16 Xl[BM][BK];
  __shared__ __align__(16) _Float16 Eh[BN][BK];
  __shared__ __align__(16) _Float16 El[BN][BK];
  __shared__ float rval[2][64][2];
  __shared__ int rixd[2][64][2];
  __shared__ int fin_idx[BM];
  __shared__ float wsum[4];

  const int tid = threadIdx.x;
  const int lane = tid & 63;
  const int wid = tid >> 6;
  const int wm = wid >> 1;
  const int wn = wid & 1;
  const int l15 = lane & 15;
  const int lq = lane >> 4;
  const int row0 = blockIdx.x * BM;

  const int srow = tid >> 1;
  const int seg16 = (tid & 1) * 16;
  const float* Xbase = X + (size_t)(row0 + srow) * D_DIM + seg16;

  float4 xgA[4], egA[4], xgB[4], egB[4];
#pragma unroll
  for (int e = 0; e < 4; ++e) xgA[e] = *(const float4*)(Xbase + e * 4);
  {
    const float* ep = E + (size_t)srow * D_DIM + seg16;
#pragma unroll
    for (int e = 0; e < 4; ++e) egA[e] = *(const float4*)(ep + e * 4);
  }

  float minv[16];
  int mini[16];
#pragma unroll
  for (int k = 0; k < 16; ++k) { minv[k] = FLT_MAX; mini[k] = 0; }

  f32x4 acc[4][4];
  float enj[4];

#define STEP(S, XG, EG, XGN, EGN)                                              \
  {                                                                            \
    const int t = (S) & (NSTEP - 1);                                           \
    const int chunk = (S) >> 4;                                                \
    if (t == 0) {                                                              \
      _Pragma("unroll") for (int j = 0; j < 4; ++j)                            \
          enj[j] = en[chunk * BN + wn * 64 + j * 16 + l15];                    \
      _Pragma("unroll") for (int i = 0; i < 4; ++i)                            \
          _Pragma("unroll") for (int j = 0; j < 4; ++j)                        \
              acc[i][j] = (f32x4)(0.f);                                        \
    }                                                                          \
    __syncthreads();                                                           \
    {                                                                          \
      f16x8 H0, H1, L0, L1;                                                    \
      cvt_hl(XG[0], H0, L0, 0); cvt_hl(XG[1], H0, L0, 4);                      \
      cvt_hl(XG[2], H1, L1, 0); cvt_hl(XG[3], H1, L1, 4);                      \
      *(f16x8*)&Xh[srow][seg16] = H0;                                          \
      *(f16x8*)&Xh[srow][seg16 + 8] = H1;                                      \
      *(f16x8*)&Xl[srow][seg16] = L0;                                          \
      *(f16x8*)&Xl[srow][seg16 + 8] = L1;                                      \
      cvt_hl(EG[0], H0, L0, 0); cvt_hl(EG[1], H0, L0, 4);                      \
      cvt_hl(EG[2], H1, L1, 0); cvt_hl(EG[3], H1, L1, 4);                      \
      *(f16x8*)&Eh[srow][seg16] = H0;                                          \
      *(f16x8*)&Eh[srow][seg16 + 8] = H1;                                      \
      *(f16x8*)&El[srow][seg16] = L0;                                          \
      *(f16x8*)&El[srow][seg16 + 8] = L1;                                      \
    }                                                                          \
    if ((S) + 1 < NS) {                                                        \
      const int t1 = ((S) + 1) & (NSTEP - 1);                                  \
      const int c1 = ((S) + 1) >> 4;                                           \
      const float* xp = Xbase + t1 * BK;                                       \
      const float* ep2 = E + (size_t)(c1 * BN + srow) * D_DIM + t1 * BK + seg16; \
      _Pragma("unroll") for (int e = 0; e < 4; ++e)                            \
          XGN[e] = *(const float4*)(xp + e * 4);                               \
      _Pragma("unroll") for (int e = 0; e < 4; ++e)                            \
          EGN[e] = *(const float4*)(ep2 + e * 4);                              \
    }                                                                          \
    __syncthreads();                                                           \
    {                                                                          \
      const int qo = lq * 8;                                                   \
      f16x8 bh[4], bl[4];                                                      \
      _Pragma("unroll") for (int j = 0; j < 4; ++j) {                          \
        bh[j] = *(const f16x8*)&Eh[wn * 64 + j * 16 + l15][qo];                \
        bl[j] = *(const f16x8*)&El[wn * 64 + j * 16 + l15][qo];                \
      }                                                                        \
      _Pragma("unroll") for (int i = 0; i < 4; ++i) {                          \
        const f16x8 ah = *(const f16x8*)&Xh[wm * 64 + i * 16 + l15][qo];       \
        const f16x8 al = *(const f16x8*)&Xl[wm * 64 + i * 16 + l15][qo];       \
        _Pragma("unroll") for (int j = 0; j < 4; ++j) {                        \
          acc[i][j] = __builtin_amdgcn_mfma_f32_16x16x32_f16(ah, bh[j], acc[i][j], 0, 0, 0); \
          acc[i][j] = __builtin_amdgcn_mfma_f32_16x16x32_f16(ah, bl[j], acc[i][j], 0, 0, 0); \
          acc[i][j] = __builtin_amdgcn_mfma_f32_16x16x32_f16(al, bh[j], acc[i][j], 0, 0, 0); \
        }                                                                      \
      }                                                                        \
    }                                                                          \
    if (t == NSTEP - 1) {                                                      \
      _Pragma("unroll") for (int i = 0; i < 4; ++i)                            \
          _Pragma("unroll") for (int j = 0; j < 4; ++j) {                      \
        const int c = chunk * BN + wn * 64 + j * 16 + l15;                     \
        _Pragma("unroll") for (int r = 0; r < 4; ++r) {                        \
          const float dd = fmaf(-2.f, acc[i][j][r], enj[j]);                   \
          const int k = i * 4 + r;                                             \
          if (dd < minv[k]) { minv[k] = dd; mini[k] = c; }                     \
        }                                                                      \
      }                                                                        \
    }                                                                          \
  }

  for (int s = 0; s < NS; s += 2) {
    STEP(s, xgA, egA, xgB, egB);
    STEP(s + 1, xgB, egB, xgA, egA);
  }
#undef STEP

#pragma unroll
  for (int k = 0; k < 16; ++k) {
    float v = minv[k];
    int ix = mini[k];
#pragma unroll
    for (int m = 1; m <= 8; m <<= 1) {
      const float v2 = __shfl_xor(v, m);
      const int ix2 = __shfl_xor(ix, m);
      if (v2 < v || (v2 == v && ix2 < ix)) { v = v2; ix = ix2; }
    }
    if (l15 == 0) {
      const int lrow = (k >> 2) * 16 + lq * 4 + (k & 3);
      rval[wm][lrow][wn] = v;
      rixd[wm][lrow][wn] = ix;
    }
  }
  __syncthreads();
  if (tid < BM) {
    const int wm_ = tid >> 6, lrow = tid & 63;
    const float v0 = rval[wm_][lrow][0], v1 = rval[wm_][lrow][1];
    const int i0 = rixd[wm_][lrow][0], i1 = rixd[wm_][lrow][1];
    fin_idx[tid] = (v1 < v0 || (v1 == v0 && i1 < i0)) ? i1 : i0;
  }
  __syncthreads();

  float lsum = 0.f;
  const int half = tid >> 7;
  const int c4 = (tid & 127) * 4;
  for (int r0 = 0; r0 < BM; r0 += 2) {
    const int r = r0 + half;
    const int idx = fin_idx[r];
    const float4 ev = *(const float4*)(E + (size_t)idx * D_DIM + c4);
    const float4 xv = *(const float4*)(X + (size_t)(row0 + r) * D_DIM + c4);
    *(float4*)(outp + (size_t)(row0 + r) * D_DIM + c4) = ev;
    const float dx = ev.x - xv.x, dy = ev.y - xv.y, dz = ev.z - xv.z, dw = ev.w - xv.w;
    lsum += dx * dx + dy * dy + dz * dz + dw * dw;
  }
#pragma unroll
  for (int m = 32; m >= 1; m >>= 1) lsum += __shfl_xor(lsum, m);
  if (lane == 0) wsum[wid] = lsum;
  __syncthreads();
  if (tid == 0) {
    const double t = (double)wsum[0] + (double)wsum[1] + (double)wsum[2] + (double)wsum[3];
    atomicAdd(loss_sum, t);
  }
}

// ---------------- finalize loss ----------------
__global__ void vq_finalize(const double* __restrict__ loss_sum, float* __restrict__ outp) {
  if (threadIdx.x == 0 && blockIdx.x == 0) {
    outp[(size_t)N_PTS * D_DIM] =
        (float)(1.25 * (*loss_sum) / ((double)N_PTS * (double)D_DIM));
  }
}

extern "C" void kernel_launch(void* const* d_in, const int* in_sizes, int n_in,
                              void* d_out, int out_size, void* d_ws, size_t ws_size,
                              hipStream_t stream) {
  const float* X = (const float*)d_in[0];
  const float* E = (const float*)d_in[1];
  float* outp = (float*)d_out;

  const size_t xpre_b = (size_t)N_PTS * D_DIM * 2 * 2;  // 128 MB
  const size_t epre_b = (size_t)K_EMB * D_DIM * 2 * 2;  // 8 MB
  const size_t en_b = (size_t)K_EMB * sizeof(float);    // 16 KB
  const size_t need = xpre_b + epre_b + en_b + 64;

  if (ws_size >= need) {
    char* Xpre = (char*)d_ws;
    char* Epre = Xpre + xpre_b;
    float* en = (float*)(Epre + epre_b);
    double* loss_sum = (double*)((char*)(en + K_EMB));

    hipMemsetAsync(loss_sum, 0, sizeof(double), stream);
    hipLaunchKernelGGL(vq_en, dim3(K_EMB / 4), dim3(256), 0, stream, E, en);
    hipLaunchKernelGGL(vq_precvt, dim3(4096 + 256), dim3(256), 0, stream, X, E, Xpre, Epre);
    hipLaunchKernelGGL(vq_main_fast, dim3(N_PTS / FBM), dim3(512), 0, stream,
                       Xpre, Epre, en, X, E, outp, loss_sum);
    hipLaunchKernelGGL(vq_finalize, dim3(1), dim3(64), 0, stream, loss_sum, outp);
  } else {
    float* en = (float*)d_ws;
    double* loss_sum = (double*)((char*)d_ws + K_EMB * sizeof(float));

    hipMemsetAsync(loss_sum, 0, sizeof(double), stream);
    hipLaunchKernelGGL(vq_en, dim3(K_EMB / 4), dim3(256), 0, stream, E, en);
    hipLaunchKernelGGL(vq_main_r2, dim3(N_PTS / BM), dim3(256), 0, stream,
                       X, E, en, outp, loss_sum);
    hipLaunchKernelGGL(vq_finalize, dim3(1), dim3(64), 0, stream, loss_sum, outp);
  }
}